// Round 7
// baseline (203.989 us; speedup 1.0000x reference)
//
#include <hip/hip_runtime.h>

// TrajLoss: sum over i of (x[i]-pred[i])^2 + (y[i]-pred[i+1])^2
// N = 16,777,216; pred has N+1 elements. Memory-bound streaming reduction.
//
// R5: algebraic re-split. Sum_i (y_i - p_{i+1})^2 == Sum_{j=1..N} (y_{j-1} - p_j)^2,
// so the thread owning pred[4i..4i+3] needs only x4[i], p4[i] (aligned) and
// y[4i-1..4i+2] (one unaligned dwordx4) — pred read once, 3 vmem insts/iter.
// R6: ALL THREE streams nontemporal. With the re-split there is zero reuse
// anywhere, so L1/L2 allocation is pure overhead. Single-variable change vs
// R5 (which regressed vs R3 despite fewer requests; R3's two nt streams are
// the suspected cause of its win).

typedef float fx4 __attribute__((ext_vector_type(4)));

__global__ void TrajLoss_zero_kernel(float* out) {
    if (threadIdx.x == 0 && blockIdx.x == 0) out[0] = 0.0f;
}

__global__ __launch_bounds__(256) void TrajLoss_6141803233879_kernel(
    const float* __restrict__ pred,
    const float* __restrict__ x,
    const float* __restrict__ y,
    float* __restrict__ out,
    int n4,   // n / 4 (float4 count)
    int n)    // total elements
{
    const int tid    = blockIdx.x * blockDim.x + threadIdx.x;
    const int stride = gridDim.x * blockDim.x;

    float a0 = 0.0f, a1 = 0.0f, a2 = 0.0f, a3 = 0.0f;
    const fx4* x4 = (const fx4*)x;
    const fx4* p4 = (const fx4*)pred;

    int i = tid;

    if (tid == 0) {
        // Peel chunk 0 (rewrite terms j=0..3: dx_0..3, dy_1..3) + boundary j=N.
        float dx, dy;
        dx = x[0] - pred[0];                       a0 += dx*dx;
        dx = x[1] - pred[1]; dy = y[0] - pred[1];  a1 += dx*dx + dy*dy;
        dx = x[2] - pred[2]; dy = y[1] - pred[2];  a2 += dx*dx + dy*dy;
        dx = x[3] - pred[3]; dy = y[2] - pred[3];  a3 += dx*dx + dy*dy;
        if ((n & 3) == 0) {
            dy = y[n - 1] - pred[n];               a0 += dy*dy;   // rewrite j=N
        } else {
            // generic tail (dead for N=16.7M)
            dy = y[(n4 << 2) - 1] - pred[n4 << 2]; a0 += dy*dy;
            for (int j = n4 << 2; j < n; ++j) {
                dx = x[j] - pred[j];
                dy = y[j] - pred[j + 1];
                a0 += dx*dx + dy*dy;
            }
        }
        i += stride;   // thread 0 skips its first generic chunk (handled above)
    }

    #pragma unroll 4
    for (; i < n4; i += stride) {
        fx4 xv = __builtin_nontemporal_load(x4 + i);
        fx4 pa = __builtin_nontemporal_load(p4 + i);                 // pred[4i..4i+3]
        fx4 yb = __builtin_nontemporal_load((const fx4*)(y + (i << 2) - 1)); // y[4i-1..4i+2]
        float dx, dy;
        dx = xv.x - pa.x; dy = yb.x - pa.x; a0 += dx*dx + dy*dy;
        dx = xv.y - pa.y; dy = yb.y - pa.y; a1 += dx*dx + dy*dy;
        dx = xv.z - pa.z; dy = yb.z - pa.z; a2 += dx*dx + dy*dy;
        dx = xv.w - pa.w; dy = yb.w - pa.w; a3 += dx*dx + dy*dy;
    }

    float acc = (a0 + a1) + (a2 + a3);

    // Wave-64 reduce
    #pragma unroll
    for (int off = 32; off > 0; off >>= 1)
        acc += __shfl_down(acc, off, 64);

    __shared__ float smem[4];   // 256 threads = 4 waves
    const int lane = threadIdx.x & 63;
    const int wave = threadIdx.x >> 6;
    if (lane == 0) smem[wave] = acc;
    __syncthreads();

    if (threadIdx.x == 0) {
        float s = smem[0] + smem[1] + smem[2] + smem[3];
        atomicAdd(out, s);   // device-scope by default on gfx950
    }
}

extern "C" void kernel_launch(void* const* d_in, const int* in_sizes, int n_in,
                              void* d_out, int out_size, void* d_ws, size_t ws_size,
                              hipStream_t stream) {
    const float* pred = (const float*)d_in[0];   // N+1 floats
    const float* x    = (const float*)d_in[1];   // N floats
    const float* y    = (const float*)d_in[2];   // N floats
    float* out = (float*)d_out;

    const int n  = in_sizes[1];
    const int n4 = n >> 2;

    TrajLoss_zero_kernel<<<1, 64, 0, stream>>>(out);

    const int block = 256;
    const int grid = 4096;   // 1,048,576 threads -> 4 float4 chunks/thread
    TrajLoss_6141803233879_kernel<<<grid, block, 0, stream>>>(pred, x, y, out, n4, n);
}

// Round 8
// 186.052 us; speedup vs baseline: 1.0964x; 1.0964x over previous
//
#include <hip/hip_runtime.h>

// TrajLoss: sum over i of (x[i]-pred[i])^2 + (y[i]-pred[i+1])^2
// N = 16,777,216; pred has N+1 elements. Memory-bound streaming reduction.
//
// R5: algebraic re-split. Sum_i (y_i - p_{i+1})^2 == Sum_{j=1..N} (y_{j-1} - p_j)^2:
// thread owning pred[4i..4i+3] needs x4[i], p4[i] (aligned) and y[4i-1..4i+2].
// R6: all three streams nontemporal (zero reuse -> cache allocation is pure
// overhead). 64.2 us = 3.14 TB/s logical.
// R7: grid 4096 -> 2048: exactly 8 resident blocks/CU, persistent for the
// whole kernel (8 chunks/thread). Single-variable test of the dispatch-churn /
// occupancy-ramp theory (OccupancyPercent was 54% with 16 short blocks/CU).
// If flat at ~64 us with occupancy >=85%, the ~3.15 TB/s per-direction
// streaming-read fabric ceiling is confirmed (m13 copy read stream = 3.15).

typedef float fx4 __attribute__((ext_vector_type(4)));

__global__ void TrajLoss_zero_kernel(float* out) {
    if (threadIdx.x == 0 && blockIdx.x == 0) out[0] = 0.0f;
}

__global__ __launch_bounds__(256) void TrajLoss_6141803233879_kernel(
    const float* __restrict__ pred,
    const float* __restrict__ x,
    const float* __restrict__ y,
    float* __restrict__ out,
    int n4,   // n / 4 (float4 count)
    int n)    // total elements
{
    const int tid    = blockIdx.x * blockDim.x + threadIdx.x;
    const int stride = gridDim.x * blockDim.x;

    float a0 = 0.0f, a1 = 0.0f, a2 = 0.0f, a3 = 0.0f;
    const fx4* x4 = (const fx4*)x;
    const fx4* p4 = (const fx4*)pred;

    int i = tid;

    if (tid == 0) {
        // Peel chunk 0 (rewrite terms j=0..3: dx_0..3, dy_1..3) + boundary j=N.
        float dx, dy;
        dx = x[0] - pred[0];                       a0 += dx*dx;
        dx = x[1] - pred[1]; dy = y[0] - pred[1];  a1 += dx*dx + dy*dy;
        dx = x[2] - pred[2]; dy = y[1] - pred[2];  a2 += dx*dx + dy*dy;
        dx = x[3] - pred[3]; dy = y[2] - pred[3];  a3 += dx*dx + dy*dy;
        if ((n & 3) == 0) {
            dy = y[n - 1] - pred[n];               a0 += dy*dy;   // rewrite j=N
        } else {
            // generic tail (dead for N=16.7M)
            dy = y[(n4 << 2) - 1] - pred[n4 << 2]; a0 += dy*dy;
            for (int j = n4 << 2; j < n; ++j) {
                dx = x[j] - pred[j];
                dy = y[j] - pred[j + 1];
                a0 += dx*dx + dy*dy;
            }
        }
        i += stride;   // thread 0 skips its first generic chunk (handled above)
    }

    #pragma unroll 8
    for (; i < n4; i += stride) {
        fx4 xv = __builtin_nontemporal_load(x4 + i);
        fx4 pa = __builtin_nontemporal_load(p4 + i);                 // pred[4i..4i+3]
        fx4 yb = __builtin_nontemporal_load((const fx4*)(y + (i << 2) - 1)); // y[4i-1..4i+2]
        float dx, dy;
        dx = xv.x - pa.x; dy = yb.x - pa.x; a0 += dx*dx + dy*dy;
        dx = xv.y - pa.y; dy = yb.y - pa.y; a1 += dx*dx + dy*dy;
        dx = xv.z - pa.z; dy = yb.z - pa.z; a2 += dx*dx + dy*dy;
        dx = xv.w - pa.w; dy = yb.w - pa.w; a3 += dx*dx + dy*dy;
    }

    float acc = (a0 + a1) + (a2 + a3);

    // Wave-64 reduce
    #pragma unroll
    for (int off = 32; off > 0; off >>= 1)
        acc += __shfl_down(acc, off, 64);

    __shared__ float smem[4];   // 256 threads = 4 waves
    const int lane = threadIdx.x & 63;
    const int wave = threadIdx.x >> 6;
    if (lane == 0) smem[wave] = acc;
    __syncthreads();

    if (threadIdx.x == 0) {
        float s = smem[0] + smem[1] + smem[2] + smem[3];
        atomicAdd(out, s);   // device-scope by default on gfx950
    }
}

extern "C" void kernel_launch(void* const* d_in, const int* in_sizes, int n_in,
                              void* d_out, int out_size, void* d_ws, size_t ws_size,
                              hipStream_t stream) {
    const float* pred = (const float*)d_in[0];   // N+1 floats
    const float* x    = (const float*)d_in[1];   // N floats
    const float* y    = (const float*)d_in[2];   // N floats
    float* out = (float*)d_out;

    const int n  = in_sizes[1];
    const int n4 = n >> 2;

    TrajLoss_zero_kernel<<<1, 64, 0, stream>>>(out);

    const int block = 256;
    // 2048 blocks = 8 resident blocks/CU on 256 CUs, persistent for the whole
    // kernel: 524,288 threads -> exactly 8 float4 chunks/thread at N=16.7M.
    const int grid = 2048;
    TrajLoss_6141803233879_kernel<<<grid, block, 0, stream>>>(pred, x, y, out, n4, n);
}

// Round 9
// 181.297 us; speedup vs baseline: 1.1252x; 1.0262x over previous
//
#include <hip/hip_runtime.h>

// TrajLoss: sum over i of (x[i]-pred[i])^2 + (y[i]-pred[i+1])^2
// N = 16,777,216; pred has N+1 elements. Memory-bound streaming reduction.
//
// R5: algebraic re-split. Sum_i (y_i - p_{i+1})^2 == Sum_{j=1..N} (y_{j-1} - p_j)^2:
// thread owning pred[4i..4i+3] needs x4[i], p4[i] (aligned) and y[4i-1..4i+2].
// R6: all three streams nontemporal (zero reuse). 64.2 us.
// R7: grid 2048 (8 persistent blocks/CU, 8 chunks/thread, full unroll):
// 45.4 us = 4.43 TB/s logical. Fewer long-lived waves with deep load batching
// beat many short waves.
// R8: continue same direction: grid 1024 (4 blocks/CU, 16 chunks/thread,
// unroll 16). If regress -> 2048 was the sweet spot.

typedef float fx4 __attribute__((ext_vector_type(4)));

__global__ void TrajLoss_zero_kernel(float* out) {
    if (threadIdx.x == 0 && blockIdx.x == 0) out[0] = 0.0f;
}

__global__ __launch_bounds__(256) void TrajLoss_6141803233879_kernel(
    const float* __restrict__ pred,
    const float* __restrict__ x,
    const float* __restrict__ y,
    float* __restrict__ out,
    int n4,   // n / 4 (float4 count)
    int n)    // total elements
{
    const int tid    = blockIdx.x * blockDim.x + threadIdx.x;
    const int stride = gridDim.x * blockDim.x;

    float a0 = 0.0f, a1 = 0.0f, a2 = 0.0f, a3 = 0.0f;
    const fx4* x4 = (const fx4*)x;
    const fx4* p4 = (const fx4*)pred;

    int i = tid;

    if (tid == 0) {
        // Peel chunk 0 (rewrite terms j=0..3: dx_0..3, dy_1..3) + boundary j=N.
        float dx, dy;
        dx = x[0] - pred[0];                       a0 += dx*dx;
        dx = x[1] - pred[1]; dy = y[0] - pred[1];  a1 += dx*dx + dy*dy;
        dx = x[2] - pred[2]; dy = y[1] - pred[2];  a2 += dx*dx + dy*dy;
        dx = x[3] - pred[3]; dy = y[2] - pred[3];  a3 += dx*dx + dy*dy;
        if ((n & 3) == 0) {
            dy = y[n - 1] - pred[n];               a0 += dy*dy;   // rewrite j=N
        } else {
            // generic tail (dead for N=16.7M)
            dy = y[(n4 << 2) - 1] - pred[n4 << 2]; a0 += dy*dy;
            for (int j = n4 << 2; j < n; ++j) {
                dx = x[j] - pred[j];
                dy = y[j] - pred[j + 1];
                a0 += dx*dx + dy*dy;
            }
        }
        i += stride;   // thread 0 skips its first generic chunk (handled above)
    }

    #pragma unroll 16
    for (; i < n4; i += stride) {
        fx4 xv = __builtin_nontemporal_load(x4 + i);
        fx4 pa = __builtin_nontemporal_load(p4 + i);                 // pred[4i..4i+3]
        fx4 yb = __builtin_nontemporal_load((const fx4*)(y + (i << 2) - 1)); // y[4i-1..4i+2]
        float dx, dy;
        dx = xv.x - pa.x; dy = yb.x - pa.x; a0 += dx*dx + dy*dy;
        dx = xv.y - pa.y; dy = yb.y - pa.y; a1 += dx*dx + dy*dy;
        dx = xv.z - pa.z; dy = yb.z - pa.z; a2 += dx*dx + dy*dy;
        dx = xv.w - pa.w; dy = yb.w - pa.w; a3 += dx*dx + dy*dy;
    }

    float acc = (a0 + a1) + (a2 + a3);

    // Wave-64 reduce
    #pragma unroll
    for (int off = 32; off > 0; off >>= 1)
        acc += __shfl_down(acc, off, 64);

    __shared__ float smem[4];   // 256 threads = 4 waves
    const int lane = threadIdx.x & 63;
    const int wave = threadIdx.x >> 6;
    if (lane == 0) smem[wave] = acc;
    __syncthreads();

    if (threadIdx.x == 0) {
        float s = smem[0] + smem[1] + smem[2] + smem[3];
        atomicAdd(out, s);   // device-scope by default on gfx950
    }
}

extern "C" void kernel_launch(void* const* d_in, const int* in_sizes, int n_in,
                              void* d_out, int out_size, void* d_ws, size_t ws_size,
                              hipStream_t stream) {
    const float* pred = (const float*)d_in[0];   // N+1 floats
    const float* x    = (const float*)d_in[1];   // N floats
    const float* y    = (const float*)d_in[2];   // N floats
    float* out = (float*)d_out;

    const int n  = in_sizes[1];
    const int n4 = n >> 2;

    TrajLoss_zero_kernel<<<1, 64, 0, stream>>>(out);

    const int block = 256;
    // 1024 blocks = 4 resident blocks/CU, persistent: 262,144 threads ->
    // exactly 16 float4 chunks/thread at N=16.7M.
    const int grid = 1024;
    TrajLoss_6141803233879_kernel<<<grid, block, 0, stream>>>(pred, x, y, out, n4, n);
}